// Round 5
// baseline (475.739 us; speedup 1.0000x reference)
//
#include <hip/hip_runtime.h>

#define BATCH 16
#define NQ 2048
#define NK 2048
#define KD 256

typedef short s16x8 __attribute__((ext_vector_type(8)));
typedef __bf16 bf16x8 __attribute__((ext_vector_type(8)));
typedef float f32x16 __attribute__((ext_vector_type(16)));
typedef float f32x4 __attribute__((ext_vector_type(4)));

static __device__ __forceinline__ unsigned short f2bf(float f) {
  unsigned u = __builtin_bit_cast(unsigned, f);
  u += 0x7FFFu + ((u >> 16) & 1u);   // round-to-nearest-even
  return (unsigned short)(u >> 16);
}

static __device__ __forceinline__ float bf2f(unsigned short h) {
  return __builtin_bit_cast(float, (unsigned)h << 16);
}

static __device__ __forceinline__ f32x16 mfma_bf16(s16x8 a, s16x8 b, f32x16 c) {
  return __builtin_amdgcn_mfma_f32_32x32x16_bf16(
      __builtin_bit_cast(bf16x8, a), __builtin_bit_cast(bf16x8, b), c, 0, 0, 0);
}

// WT[n][k] = W[k][n] * scale, cast to bf16.  Grid: (256, 2) x 256 thr.
// y==0: Wk (scale 1), y==1: Wq (scale 1/16, folds 1/sqrt(256)).
__global__ void prep_wt(const float* __restrict__ Wk, unsigned short* __restrict__ WkT,
                        const float* __restrict__ Wq, unsigned short* __restrict__ WqT) {
  const float* W = blockIdx.y ? Wq : Wk;
  unsigned short* WT = blockIdx.y ? WqT : WkT;
  float scale = blockIdx.y ? 0.0625f : 1.0f;
  int idx = blockIdx.x * 256 + threadIdx.x;
  int n = idx >> 8, k = idx & 255;
  WT[n * 256 + k] = f2bf(W[k * 256 + n] * scale);
}

// Projection, output written in MFMA-FRAGMENT order:
//   Yf[((g*16 + kk)*64 + khe*32 + n31)*8 + j]  holds  Y[row=g*32+n31][e=kk*16+khe*8+j]
// where g = global 32-row tile (b*64 + n>>5).  A fragment load in attn is then
// 64 lanes x consecutive 16 B = 1 KB coalesced.
__global__ __launch_bounds__(256, 2) void proj_kernel(
    const float* __restrict__ Xk, const unsigned short* __restrict__ WkT,
    unsigned short* __restrict__ Yk,
    const float* __restrict__ Xq, const unsigned short* __restrict__ WqT,
    unsigned short* __restrict__ Yq) {
  const float* X;
  const unsigned short* WT;
  unsigned short* Y;
  if (blockIdx.y == 0) { X = Xk; WT = WkT; Y = Yk; }
  else                 { X = Xq; WT = WqT; Y = Yq; }

  int tid = threadIdx.x;
  int wave = tid >> 6, lane = tid & 63;
  int l31 = lane & 31, kh = lane >> 5;
  int r0 = blockIdx.x * 128 + wave * 32;

  const float* xp = X + (size_t)(r0 + l31) * 256 + kh * 8;

  f32x16 acc[8];
#pragma unroll
  for (int ct = 0; ct < 8; ++ct)
#pragma unroll
    for (int i = 0; i < 16; ++i) acc[ct][i] = 0.0f;

#pragma unroll
  for (int kk = 0; kk < 16; ++kk) {
    f32x4 a0 = *(const f32x4*)(xp + kk * 16);
    f32x4 a1 = *(const f32x4*)(xp + kk * 16 + 4);
    s16x8 af;
#pragma unroll
    for (int j = 0; j < 4; ++j) {
      af[j]     = (short)f2bf(a0[j]);
      af[4 + j] = (short)f2bf(a1[j]);
    }
#pragma unroll
    for (int ct = 0; ct < 8; ++ct) {
      s16x8 bw = *(const s16x8*)(WT + (size_t)(ct * 32 + l31) * 256 + kk * 16 + kh * 8);
      acc[ct] = mfma_bf16(af, bw, acc[ct]);
    }
  }

  size_t gbase = (size_t)(r0 >> 5) * 16;   // global 32-row tile index * 16
#pragma unroll
  for (int ct = 0; ct < 8; ++ct) {
    int ecol = ct * 32 + l31;
    size_t cbase = (gbase + (ecol >> 4)) * 64 * 8 + ((ecol >> 3) & 1) * 32 * 8 + (ecol & 7);
#pragma unroll
    for (int r = 0; r < 16; ++r) {
      int rrow = (r & 3) + 8 * (r >> 2) + 4 * kh;   // n31 within the tile
      Y[cbase + rrow * 8] = f2bf(acc[ct][r]);
    }
  }
}

// Fused adjacency-pack + scores + tanh-clip + mask + softmax.
// Grid: (64, 16) = 1024 blocks, 512 threads (8 waves).
// __launch_bounds__(512, 4): 4 waves/SIMD -> 2 blocks/CU resident (VGPR<=128).
// XCD-aware remap: xcd = lin&7 owns batches {2*xcd, 2*xcd+1} so each XCD's
// L2 holds exactly 2 MB of K panels.
__global__ __launch_bounds__(512, 4) void attn_kernel(
    const unsigned short* __restrict__ Kf, const unsigned short* __restrict__ Qf,
    const int* __restrict__ adj, float* __restrict__ out) {
  int lin = blockIdx.y * 64 + blockIdx.x;
  int b  = (lin & 7) * 2 + ((lin >> 3) & 1);
  int qt = lin >> 4;
  int q0 = qt * 32;
  int tid = threadIdx.x;
  int wave = tid >> 6, lane = tid & 63;
  int l31 = lane & 31, kh = lane >> 5;
  int colbase = wave * 256;

  __shared__ unsigned lmask[32 * 64];  // 8 KB: mask bits, 32 rows x 2048 cols
  __shared__ float wsum[8][32];
  __shared__ float rrecip[32];

  // ---- pack adjacency into LDS bitmask: wave w handles rows w*4 .. w*4+3 ----
  const int* abase = adj + ((size_t)b * NQ + q0) * (size_t)NK;
#pragma unroll
  for (int rr4 = 0; rr4 < 4; ++rr4) {
    int rr = wave * 4 + rr4;
    const int* ap = abase + (size_t)rr * NK + lane;
    int av[32];
#pragma unroll
    for (int c = 0; c < 32; ++c) av[c] = ap[c * 64];
    unsigned my = 0;
#pragma unroll
    for (int c = 0; c < 32; ++c) {
      unsigned long long m = __ballot(av[c] != 0);
      if ((lane >> 1) == c) my = (lane & 1) ? (unsigned)(m >> 32) : (unsigned)m;
    }
    lmask[rr * 64 + lane] = my;   // word w covers cols w*32..w*32+31, bit = col&31
  }

  // Q fragments: tile g = b*64 + qt, coalesced
  const unsigned short* qp = Qf + ((size_t)(b * 64 + qt) * 16) * 512;
  s16x8 aq[16];
#pragma unroll
  for (int kk = 0; kk < 16; ++kk)
    aq[kk] = *(const s16x8*)(qp + (kk * 64 + lane) * 8);

  const unsigned short* kfb = Kf + ((size_t)b * 64 * 16) * 512;

  __syncthreads();  // lmask ready

  float rsum[16];
#pragma unroll
  for (int r = 0; r < 16; ++r) rsum[r] = 0.0f;

  s16x8 pst[8][2];  // unnormalized P, bf16, 16 values per col-tile
  unsigned bit = 1u << l31;

#pragma unroll
  for (int ct = 0; ct < 8; ++ct) {
    f32x16 acc;
#pragma unroll
    for (int i = 0; i < 16; ++i) acc[i] = 0.0f;

    const unsigned short* kpt = kfb + ((size_t)(wave * 8 + ct) * 16) * 512;
#pragma unroll
    for (int kk = 0; kk < 16; ++kk) {
      s16x8 bk = *(const s16x8*)(kpt + (kk * 64 + lane) * 8);
      acc = mfma_bf16(aq[kk], bk, acc);
    }

#pragma unroll
    for (int r = 0; r < 16; ++r) {
      int rrow = (r & 3) + 8 * (r >> 2) + 4 * kh;
      unsigned mw = lmask[rrow * 64 + wave * 8 + ct];
      float s = acc[r];                                   // scale folded into Wq
      float u  = __builtin_amdgcn_exp2f(s * 2.885390081777927f);   // e^(2s)
      float th = 1.0f - 2.0f * __builtin_amdgcn_rcpf(u + 1.0f);    // tanh(s)
      float e  = __builtin_amdgcn_exp2f((10.0f * th - 10.0f) * 1.44269504088896f);
      float p  = (mw & bit) ? e : 0.0f;
      rsum[r] += p;
      pst[ct][r >> 3][r & 7] = (short)f2bf(p);
    }
  }

  // reduce row sums across the 32 cols of this half-wave (rows differ by kh)
#pragma unroll
  for (int r = 0; r < 16; ++r) {
    float v = rsum[r];
    v += __shfl_xor(v, 1);
    v += __shfl_xor(v, 2);
    v += __shfl_xor(v, 4);
    v += __shfl_xor(v, 8);
    v += __shfl_xor(v, 16);
    rsum[r] = v;
  }
  if (l31 == 0) {
#pragma unroll
    for (int r = 0; r < 16; ++r)
      wsum[wave][(r & 3) + 8 * (r >> 2) + 4 * kh] = rsum[r];
  }
  __syncthreads();
  if (tid < 32) {
    float s = 0.0f;
#pragma unroll
    for (int w = 0; w < 8; ++w) s += wsum[w][tid];
    rrecip[tid] = 1.0f / s;
  }
  __syncthreads();

  float rc[16];
#pragma unroll
  for (int r = 0; r < 16; ++r) rc[r] = rrecip[(r & 3) + 8 * (r >> 2) + 4 * kh];

  float* op = out + ((size_t)b * NQ + q0) * (size_t)NK + colbase + l31;
#pragma unroll
  for (int ct = 0; ct < 8; ++ct) {
#pragma unroll
    for (int r = 0; r < 16; ++r) {
      int rrow = (r & 3) + 8 * (r >> 2) + 4 * kh;
      float pf = bf2f((unsigned short)pst[ct][r >> 3][r & 7]);
      op[(size_t)rrow * NK + ct * 32] = pf * rc[r];
    }
  }
}

extern "C" void kernel_launch(void* const* d_in, const int* in_sizes, int n_in,
                              void* d_out, int out_size, void* d_ws, size_t ws_size,
                              hipStream_t stream) {
  const float* k_in = (const float*)d_in[0];
  const float* q_in = (const float*)d_in[1];
  const int* adj    = (const int*)d_in[2];
  const float* Wk   = (const float*)d_in[3];
  const float* Wq   = (const float*)d_in[4];
  float* out = (float*)d_out;

  char* ws = (char*)d_ws;
  unsigned short* WkT = (unsigned short*)(ws);                           // 128 KB
  unsigned short* WqT = (unsigned short*)(ws + (1u << 17));              // 128 KB
  unsigned short* Kf  = (unsigned short*)(ws + (1u << 18));              // 16 MB
  unsigned short* Qf  = (unsigned short*)(ws + (1u << 18) + (1u << 24)); // 16 MB

  prep_wt<<<dim3(256, 2), 256, 0, stream>>>(Wk, WkT, Wq, WqT);

  proj_kernel<<<dim3(256, 2), 256, 0, stream>>>(k_in, WkT, Kf, q_in, WqT, Qf);

  attn_kernel<<<dim3(64, 16), 512, 0, stream>>>(Kf, Qf, adj, out);
}

// Round 6
// 260.508 us; speedup vs baseline: 1.8262x; 1.8262x over previous
//
#include <hip/hip_runtime.h>

#define BATCH 16
#define NQ 2048
#define NK 2048
#define KD 256

typedef short s16x8 __attribute__((ext_vector_type(8)));
typedef __bf16 bf16x8 __attribute__((ext_vector_type(8)));
typedef float f32x16 __attribute__((ext_vector_type(16)));
typedef float f32x4 __attribute__((ext_vector_type(4)));

static __device__ __forceinline__ unsigned short f2bf(float f) {
  unsigned u = __builtin_bit_cast(unsigned, f);
  u += 0x7FFFu + ((u >> 16) & 1u);   // round-to-nearest-even
  return (unsigned short)(u >> 16);
}

static __device__ __forceinline__ float bf2f(unsigned short h) {
  return __builtin_bit_cast(float, (unsigned)h << 16);
}

static __device__ __forceinline__ f32x16 mfma_bf16(s16x8 a, s16x8 b, f32x16 c) {
  return __builtin_amdgcn_mfma_f32_32x32x16_bf16(
      __builtin_bit_cast(bf16x8, a), __builtin_bit_cast(bf16x8, b), c, 0, 0, 0);
}

// WT[n][k] = W[k][n] * scale, cast to bf16.  Grid: (256, 2) x 256 thr.
// y==0: Wk (scale 1), y==1: Wq (scale 1/16, folds 1/sqrt(256)).
__global__ void prep_wt(const float* __restrict__ Wk, unsigned short* __restrict__ WkT,
                        const float* __restrict__ Wq, unsigned short* __restrict__ WqT) {
  const float* W = blockIdx.y ? Wq : Wk;
  unsigned short* WT = blockIdx.y ? WqT : WkT;
  float scale = blockIdx.y ? 0.0625f : 1.0f;
  int idx = blockIdx.x * 256 + threadIdx.x;
  int n = idx >> 8, k = idx & 255;
  WT[n * 256 + k] = f2bf(W[k * 256 + n] * scale);
}

// Projection, output written in MFMA-FRAGMENT order:
//   Yf[((g*16 + kk)*64 + khe*32 + n31)*8 + j]  holds  Y[row=g*32+n31][e=kk*16+khe*8+j]
// where g = global 32-row tile (b*64 + n>>5).  A fragment load in attn is then
// 64 lanes x consecutive 16 B = 1 KB coalesced.
__global__ __launch_bounds__(256, 2) void proj_kernel(
    const float* __restrict__ Xk, const unsigned short* __restrict__ WkT,
    unsigned short* __restrict__ Yk,
    const float* __restrict__ Xq, const unsigned short* __restrict__ WqT,
    unsigned short* __restrict__ Yq) {
  const float* X;
  const unsigned short* WT;
  unsigned short* Y;
  if (blockIdx.y == 0) { X = Xk; WT = WkT; Y = Yk; }
  else                 { X = Xq; WT = WqT; Y = Yq; }

  int tid = threadIdx.x;
  int wave = tid >> 6, lane = tid & 63;
  int l31 = lane & 31, kh = lane >> 5;
  int r0 = blockIdx.x * 128 + wave * 32;

  const float* xp = X + (size_t)(r0 + l31) * 256 + kh * 8;

  f32x16 acc[8];
#pragma unroll
  for (int ct = 0; ct < 8; ++ct)
#pragma unroll
    for (int i = 0; i < 16; ++i) acc[ct][i] = 0.0f;

#pragma unroll
  for (int kk = 0; kk < 16; ++kk) {
    f32x4 a0 = *(const f32x4*)(xp + kk * 16);
    f32x4 a1 = *(const f32x4*)(xp + kk * 16 + 4);
    s16x8 af;
#pragma unroll
    for (int j = 0; j < 4; ++j) {
      af[j]     = (short)f2bf(a0[j]);
      af[4 + j] = (short)f2bf(a1[j]);
    }
#pragma unroll
    for (int ct = 0; ct < 8; ++ct) {
      s16x8 bw = *(const s16x8*)(WT + (size_t)(ct * 32 + l31) * 256 + kk * 16 + kh * 8);
      acc[ct] = mfma_bf16(af, bw, acc[ct]);
    }
  }

  size_t gbase = (size_t)(r0 >> 5) * 16;   // global 32-row tile index * 16
#pragma unroll
  for (int ct = 0; ct < 8; ++ct) {
    int ecol = ct * 32 + l31;
    size_t cbase = (gbase + (ecol >> 4)) * 64 * 8 + ((ecol >> 3) & 1) * 32 * 8 + (ecol & 7);
#pragma unroll
    for (int r = 0; r < 16; ++r) {
      int rrow = (r & 3) + 8 * (r >> 2) + 4 * kh;   // n31 within the tile
      Y[cbase + rrow * 8] = f2bf(acc[ct][r]);
    }
  }
}

// Fused adjacency-pack + scores + tanh-clip + mask + softmax.
// Grid: (64, 16) = 1024 blocks, 512 threads (8 waves).
// Wave-LOCAL adjacency pack: wave w packs mask words for its own cols
// [w*256, w*256+256) for all 32 rows -> NO barrier between pack and compute;
// one wave's adjacency streaming overlaps other waves' MFMA/score work.
// __launch_bounds__(512, 2): reproduces the known-good 128-VGPR codegen
// (512,4 forced a 64-VGPR spill disaster: +530 MB scratch traffic, 2x slower).
// XCD-aware remap: xcd = lin&7 owns batches {2*xcd, 2*xcd+1} so each XCD's
// L2 holds exactly 2 MB of K panels.
__global__ __launch_bounds__(512, 2) void attn_kernel(
    const unsigned short* __restrict__ Kf, const unsigned short* __restrict__ Qf,
    const int* __restrict__ adj, float* __restrict__ out) {
  int lin = blockIdx.y * 64 + blockIdx.x;
  int b  = (lin & 7) * 2 + ((lin >> 3) & 1);
  int qt = lin >> 4;
  int q0 = qt * 32;
  int tid = threadIdx.x;
  int wave = tid >> 6, lane = tid & 63;
  int l31 = lane & 31, kh = lane >> 5;
  int colbase = wave * 256;

  __shared__ unsigned lmask[8 * 256];  // 8 KB: [wave][row 0..31][word 0..7]
  __shared__ float wsum[8][32];
  __shared__ float rrecip[32];

  // Q fragments first (in flight during the pack): tile g = b*64 + qt
  const unsigned short* qp = Qf + ((size_t)(b * 64 + qt) * 16) * 512;
  s16x8 aq[16];
#pragma unroll
  for (int kk = 0; kk < 16; ++kk)
    aq[kk] = *(const s16x8*)(qp + (kk * 64 + lane) * 8);

  // ---- wave-local pack: cols [wave*256, wave*256+256) for rows 0..31 ----
  const int* abase = adj + ((size_t)b * NQ + q0) * (size_t)NK + colbase + lane;
  unsigned* lm = lmask + wave * 256;
#pragma unroll
  for (int rg = 0; rg < 4; ++rg) {
    int av[8][4];
#pragma unroll
    for (int r8 = 0; r8 < 8; ++r8) {
      const int* ap = abase + (size_t)(rg * 8 + r8) * NK;
#pragma unroll
      for (int cc = 0; cc < 4; ++cc) av[r8][cc] = ap[cc * 64];
    }
#pragma unroll
    for (int r8 = 0; r8 < 8; ++r8) {
      unsigned long long b0 = __ballot(av[r8][0] != 0);   // cols 0..63 of range
      unsigned long long b1 = __ballot(av[r8][1] != 0);   // cols 64..127
      unsigned long long b2 = __ballot(av[r8][2] != 0);   // cols 128..191
      unsigned long long b3 = __ballot(av[r8][3] != 0);   // cols 192..255
      if (lane < 8) {   // lane j stores word j (cols j*32 .. j*32+31)
        unsigned long long bb = (lane & 4) ? ((lane & 2) ? b3 : b2)
                                           : ((lane & 2) ? b1 : b0);
        unsigned word = (lane & 1) ? (unsigned)(bb >> 32) : (unsigned)bb;
        lm[(rg * 8 + r8) * 8 + lane] = word;
      }
    }
  }
  // NO __syncthreads: each wave reads only its own lmask slice (same-wave
  // LDS write->read ordering is handled by lgkmcnt).

  const unsigned short* kfb = Kf + ((size_t)b * 64 * 16) * 512;

  float rsum[16];
#pragma unroll
  for (int r = 0; r < 16; ++r) rsum[r] = 0.0f;

  s16x8 pst[8][2];  // unnormalized P, bf16, 16 values per col-tile
  unsigned bit = 1u << l31;

#pragma unroll
  for (int ct = 0; ct < 8; ++ct) {
    f32x16 acc;
#pragma unroll
    for (int i = 0; i < 16; ++i) acc[i] = 0.0f;

    const unsigned short* kpt = kfb + ((size_t)(wave * 8 + ct) * 16) * 512;
#pragma unroll
    for (int kk = 0; kk < 16; ++kk) {
      s16x8 bk = *(const s16x8*)(kpt + (kk * 64 + lane) * 8);
      acc = mfma_bf16(aq[kk], bk, acc);
    }

#pragma unroll
    for (int r = 0; r < 16; ++r) {
      int rrow = (r & 3) + 8 * (r >> 2) + 4 * kh;
      unsigned mw = lm[rrow * 8 + ct];
      float s = acc[r];                                   // scale folded into Wq
      float u  = __builtin_amdgcn_exp2f(s * 2.885390081777927f);   // e^(2s)
      float th = 1.0f - 2.0f * __builtin_amdgcn_rcpf(u + 1.0f);    // tanh(s)
      float e  = __builtin_amdgcn_exp2f((10.0f * th - 10.0f) * 1.44269504088896f);
      float p  = (mw & bit) ? e : 0.0f;
      rsum[r] += p;
      pst[ct][r >> 3][r & 7] = (short)f2bf(p);
    }
  }

  // reduce row sums across the 32 cols of this half-wave (rows differ by kh)
#pragma unroll
  for (int r = 0; r < 16; ++r) {
    float v = rsum[r];
    v += __shfl_xor(v, 1);
    v += __shfl_xor(v, 2);
    v += __shfl_xor(v, 4);
    v += __shfl_xor(v, 8);
    v += __shfl_xor(v, 16);
    rsum[r] = v;
  }
  if (l31 == 0) {
#pragma unroll
    for (int r = 0; r < 16; ++r)
      wsum[wave][(r & 3) + 8 * (r >> 2) + 4 * kh] = rsum[r];
  }
  __syncthreads();
  if (tid < 32) {
    float s = 0.0f;
#pragma unroll
    for (int w = 0; w < 8; ++w) s += wsum[w][tid];
    rrecip[tid] = 1.0f / s;
  }
  __syncthreads();

  float rc[16];
#pragma unroll
  for (int r = 0; r < 16; ++r) rc[r] = rrecip[(r & 3) + 8 * (r >> 2) + 4 * kh];

  float* op = out + ((size_t)b * NQ + q0) * (size_t)NK + colbase + l31;
#pragma unroll
  for (int ct = 0; ct < 8; ++ct) {
#pragma unroll
    for (int r = 0; r < 16; ++r) {
      int rrow = (r & 3) + 8 * (r >> 2) + 4 * kh;
      float pf = bf2f((unsigned short)pst[ct][r >> 3][r & 7]);
      op[(size_t)rrow * NK + ct * 32] = pf * rc[r];
    }
  }
}

extern "C" void kernel_launch(void* const* d_in, const int* in_sizes, int n_in,
                              void* d_out, int out_size, void* d_ws, size_t ws_size,
                              hipStream_t stream) {
  const float* k_in = (const float*)d_in[0];
  const float* q_in = (const float*)d_in[1];
  const int* adj    = (const int*)d_in[2];
  const float* Wk   = (const float*)d_in[3];
  const float* Wq   = (const float*)d_in[4];
  float* out = (float*)d_out;

  char* ws = (char*)d_ws;
  unsigned short* WkT = (unsigned short*)(ws);                           // 128 KB
  unsigned short* WqT = (unsigned short*)(ws + (1u << 17));              // 128 KB
  unsigned short* Kf  = (unsigned short*)(ws + (1u << 18));              // 16 MB
  unsigned short* Qf  = (unsigned short*)(ws + (1u << 18) + (1u << 24)); // 16 MB

  prep_wt<<<dim3(256, 2), 256, 0, stream>>>(Wk, WkT, Wq, WqT);

  proj_kernel<<<dim3(256, 2), 256, 0, stream>>>(k_in, WkT, Kf, q_in, WqT, Qf);

  attn_kernel<<<dim3(64, 16), 512, 0, stream>>>(Kf, Qf, adj, out);
}